// Round 1
// 5163.215 us; speedup vs baseline: 7.2400x; 7.2400x over previous
//
#include <hip/hip_runtime.h>

// Problem: tanh-RNN. inputs (B,S) int tokens; x_proj = W_ih^T[token] + b_ih + b_hh;
// h_t = tanh(x_t + h_{t-1} @ W_hh^T); out = Y @ W_lin^T + b_lin ; also return h_T.
#define B_ 32
#define S_ 1024
#define V_ 2048
#define H_ 1024
#define OUT_ELEMS (S_*B_*V_)   // 67108864 fp32 outputs, then B_*H_ fp32 h_T tail

typedef _Float16 f16;
typedef __attribute__((ext_vector_type(2))) _Float16 f16x2;
typedef __attribute__((ext_vector_type(8))) _Float16 f16x8;
typedef __attribute__((ext_vector_type(4))) float    f32x4;

// ---- workspace layout (bytes) ----
#define WS_YH    0ul                  // S*B*H f16  = 64 MB   (Y, fp16, row = t*B+b)
#define WS_E     67108864ul           // V*H  f32   = 8 MB    (E[v][i] = W_ih[i][v]+b_ih[i]+b_hh[i])
#define WS_WL16  75497472ul           // V*H  f16   = 4 MB    (W_lin cast)
#define WS_H16   79691776ul           // 2*B*H f16  = 128 KB  (h double buffer)
#define WS_TOK   79822848ul           // S*B  i32   = 128 KB  (tokens transposed [t][b])
#define WS_FLAGS 79953920ul           // 256 u32              (group barrier flags)

#if __has_builtin(__builtin_amdgcn_fdot2)
#define FDOT2(a,b,c) __builtin_amdgcn_fdot2((a),(b),(c),false)
#else
#define FDOT2(a,b,c) ((float)(a)[0]*(float)(b)[0] + (float)(a)[1]*(float)(b)[1] + (c))
#endif
#define PAIR(v,q) (__builtin_shufflevector((v),(v), 2*(q), 2*(q)+1))

// ---------------- prep: build E, cast W_lin, transpose tokens, init h0, zero flags -----
__global__ void prep_kernel(const int* __restrict__ tok_in,   // (B,S) int32
                            const float* __restrict__ state,  // (1,B,H)
                            const float* __restrict__ W_ih,   // (H,V)
                            const float* __restrict__ b_ih,
                            const float* __restrict__ b_hh,
                            const float* __restrict__ W_lin,  // (V,H)
                            char* __restrict__ ws)
{
    float* E      = (float*)(ws + WS_E);
    f16*   WL     = (f16*)  (ws + WS_WL16);
    f16*   h16    = (f16*)  (ws + WS_H16);
    int*   tok    = (int*)  (ws + WS_TOK);
    unsigned* flg = (unsigned*)(ws + WS_FLAGS);

    long idx = (long)blockIdx.x * blockDim.x + threadIdx.x;
    if (idx < (long)V_*H_) {                 // E build: lanes consecutive in v -> coalesced W_ih reads
        int i = (int)(idx >> 11);            // / V_
        int v = (int)(idx & (V_-1));
        E[(long)v*H_ + i] = W_ih[(long)i*V_ + v] + b_ih[i] + b_hh[i];
        return;
    }
    long o = idx - (long)V_*H_;
    if (o < (long)V_*H_) { WL[o] = (f16)W_lin[o]; return; }
    long o2 = o - (long)V_*H_;
    if (o2 < S_*B_) {                        // tok[t][b] = inputs[b][t]
        int t = (int)(o2 >> 5), b = (int)(o2 & 31);
        tok[o2] = tok_in[b*S_ + t];
        return;
    }
    long o3 = o2 - S_*B_;
    if (o3 < B_*H_) { h16[o3] = (f16)state[o3]; return; }
    long o4 = o3 - B_*H_;
    if (o4 < 256) flg[o4] = 0u;
}

// ---------------- persistent recurrence ----------------
// 256 blocks: bg = blockIdx%8 (batch group of 4), hb = blockIdx/8 (32 hidden rows).
// W_hh rows held fp16 in bank-swizzled LDS (64 KB). Per step: stage the group's h slice
// (8 KB) from the coherent point into LDS via system-scope (sc0 sc1) loads, dot-product
// from LDS, write h back with system-scope write-through stores, then a flag
// release/poll with sc0 sc1 accesses. NO cache-wide fences (no buffer_wbl2/inv) — the
// old __threadfence() pair cost ~36 us/step in L2 writeback/invalidate serialization.
__launch_bounds__(256, 1)
__global__ void rnn_kernel(const float* __restrict__ W_hh,
                           char* __restrict__ ws,
                           float* __restrict__ d_out)
{
    __shared__ f16 Wt[32 * H_];                       // 64 KB
    __shared__ __align__(16) f16 hl[4 * H_];          // 8 KB staged h (4 batches x H)

    const int tid = threadIdx.x;
    const int bg  = blockIdx.x & 7;
    const int hb  = blockIdx.x >> 3;
    const int i0  = hb * 32;

    float* E       = (float*)(ws + WS_E);
    f16*   Yh      = (f16*)  (ws + WS_YH);
    f16*   h16     = (f16*)  (ws + WS_H16);
    const int* tok = (const int*)(ws + WS_TOK);
    unsigned* flg  = (unsigned*)(ws + WS_FLAGS);
    const int myflag = bg*32 + hb;

    // Load W slice into swizzled LDS: j-pair p=(j>>1) at dword p*32 + ((r + 4*(j>>7)) & 31)
    for (int e = tid; e < 32*H_; e += 256) {
        int rr = e >> 10, j = e & (H_-1);
        int slot = (rr + 4*(j >> 7)) & 31;
        Wt[(((j>>1)*32 + slot) << 1) | (j & 1)] = (f16)W_hh[(long)(i0+rr)*H_ + j];
    }
    __syncthreads();

    const int jp = tid & 7;          // 8 j-slices of 128
    const int r  = tid >> 3;         // 32 rows
    const f16x2* Wd = (const f16x2*)Wt;
    const int wbase = jp*2048 + ((r + 4*jp) & 31);
    unsigned long long* const l64 = (unsigned long long*)hl;

    for (int t = 0; t < S_; ++t) {
        const int cur = t & 1, nxt = cur ^ 1;

        // ---- stage h[cur] for our 4 batches (8 KB) via system-scope loads ----
        {
            const unsigned long long* s64 =
                (const unsigned long long*)(h16 + (long)cur*(B_*H_) + (long)(bg*4)*H_);
            unsigned long long d0, d1, d2, d3;
            asm volatile("global_load_dwordx2 %0, %1, off sc0 sc1" : "=v"(d0) : "v"(s64 + tid      ) : "memory");
            asm volatile("global_load_dwordx2 %0, %1, off sc0 sc1" : "=v"(d1) : "v"(s64 + tid + 256) : "memory");
            asm volatile("global_load_dwordx2 %0, %1, off sc0 sc1" : "=v"(d2) : "v"(s64 + tid + 512) : "memory");
            asm volatile("global_load_dwordx2 %0, %1, off sc0 sc1" : "=v"(d3) : "v"(s64 + tid + 768) : "memory");
            asm volatile("s_waitcnt vmcnt(0)" ::: "memory");
            l64[tid      ] = d0;
            l64[tid + 256] = d1;
            l64[tid + 512] = d2;
            l64[tid + 768] = d3;
        }
        __syncthreads();

        float a0=0.f, a1=0.f, a2=0.f, a3=0.f;
        #pragma unroll
        for (int c = 0; c < 16; ++c) {
            const int cc = (c + 2*jp) & 15;   // per-jp rotation: LDS h reads 2-way (free)
            f16x2 w0 = Wd[wbase + cc*128];
            f16x2 w1 = Wd[wbase + cc*128 + 32];
            f16x2 w2 = Wd[wbase + cc*128 + 64];
            f16x2 w3 = Wd[wbase + cc*128 + 96];
            const f16* hb_ = hl + jp*128 + cc*8;
            f16x8 v0 = *(const f16x8*)(hb_ + 0*H_);
            f16x8 v1 = *(const f16x8*)(hb_ + 1*H_);
            f16x8 v2 = *(const f16x8*)(hb_ + 2*H_);
            f16x8 v3 = *(const f16x8*)(hb_ + 3*H_);
            a0 = FDOT2(w0, PAIR(v0,0), a0); a0 = FDOT2(w1, PAIR(v0,1), a0);
            a0 = FDOT2(w2, PAIR(v0,2), a0); a0 = FDOT2(w3, PAIR(v0,3), a0);
            a1 = FDOT2(w0, PAIR(v1,0), a1); a1 = FDOT2(w1, PAIR(v1,1), a1);
            a1 = FDOT2(w2, PAIR(v1,2), a1); a1 = FDOT2(w3, PAIR(v1,3), a1);
            a2 = FDOT2(w0, PAIR(v2,0), a2); a2 = FDOT2(w1, PAIR(v2,1), a2);
            a2 = FDOT2(w2, PAIR(v2,2), a2); a2 = FDOT2(w3, PAIR(v2,3), a2);
            a3 = FDOT2(w0, PAIR(v3,0), a3); a3 = FDOT2(w1, PAIR(v3,1), a3);
            a3 = FDOT2(w2, PAIR(v3,2), a3); a3 = FDOT2(w3, PAIR(v3,3), a3);
        }
        // reduce over jp (8 adjacent lanes)
        a0 += __shfl_xor(a0,1); a0 += __shfl_xor(a0,2); a0 += __shfl_xor(a0,4);
        a1 += __shfl_xor(a1,1); a1 += __shfl_xor(a1,2); a1 += __shfl_xor(a1,4);
        a2 += __shfl_xor(a2,1); a2 += __shfl_xor(a2,2); a2 += __shfl_xor(a2,4);
        a3 += __shfl_xor(a3,1); a3 += __shfl_xor(a3,2); a3 += __shfl_xor(a3,4);

        if (jp == 0) {
            const float hv[4] = {a0, a1, a2, a3};
            unsigned hpk[4];
            float hnv[4];
            #pragma unroll
            for (int b = 0; b < 4; ++b) {
                const int token = tok[t*B_ + bg*4 + b];
                const float x = E[(long)token*H_ + i0 + r];
                const float hn = tanhf(x + hv[b]);
                hnv[b] = hn;
                // pack rows (r, r+1) into one u32 (coherent stores need >= 4B)
                unsigned hbits = (unsigned)__builtin_bit_cast(unsigned short, (f16)hn);
                unsigned up    = __shfl_down(hbits, 8);   // row r+1's value (lane tid+8)
                hpk[b] = hbits | (up << 16);
            }
            if ((tid & 15) == 0) {       // even r: store the f16x2 pair for rows r, r+1
                #pragma unroll
                for (int b = 0; b < 4; ++b) {
                    const int gb = bg*4 + b;
                    *(unsigned*)(Yh + (long)(t*B_ + gb)*H_ + i0 + r) = hpk[b];   // plain
                    unsigned* hdst = (unsigned*)(h16 + (long)nxt*(B_*H_) + (long)gb*H_ + i0 + r);
                    asm volatile("global_store_dword %0, %1, off sc0 sc1"
                                 :: "v"(hdst), "v"(hpk[b]) : "memory");          // coherent
                }
            }
            if (t == S_-1) {
                #pragma unroll
                for (int b = 0; b < 4; ++b)
                    d_out[OUT_ELEMS + (bg*4+b)*H_ + i0 + r] = hnv[b];  // h_T tail (fp32)
            }
        }
        // drain every wave's stores to the coherent point, then publish the flag
        asm volatile("s_waitcnt vmcnt(0)" ::: "memory");
        __syncthreads();

        if (t < S_-1) {
            if (tid == 0) {
                unsigned fv = (unsigned)(t+1);
                asm volatile("global_store_dword %0, %1, off sc0 sc1"
                             :: "v"(&flg[myflag]), "v"(fv) : "memory");
            }
            if (tid < 32) {
                const unsigned tgt = (unsigned)(t+1);
                const unsigned* fp = &flg[bg*32 + tid];
                unsigned fv;
                for (;;) {
                    asm volatile("global_load_dword %0, %1, off sc0 sc1\n\t"
                                 "s_waitcnt vmcnt(0)"
                                 : "=v"(fv) : "v"(fp) : "memory");
                    if (fv >= tgt) break;
                    __builtin_amdgcn_s_sleep(2);
                }
            }
            __syncthreads();
        }
    }
}

// ---------------- output GEMM: C = Yh @ WL^T + b_lin (fp16 MFMA, fp32 acc) ------------
#define AST 40   // LDS row stride in f16: 32 + 8 pad -> 16B aligned, frag reads 2-way (free)
__launch_bounds__(256, 2)
__global__ void out_gemm(const char* __restrict__ ws,
                         const float* __restrict__ b_lin,
                         float* __restrict__ d_out)
{
    __shared__ f16 Al[128*AST];
    __shared__ f16 Bl[128*AST];
    const f16* Yh = (const f16*)(ws + WS_YH);
    const f16* WL = (const f16*)(ws + WS_WL16);

    const int tid = threadIdx.x;
    const int nt = blockIdx.x & 15;
    const int mt = blockIdx.x >> 4;
    const long m0 = (long)mt * 128;
    const int  n0 = nt * 128;

    const int lane = tid & 63;
    const int wave = tid >> 6;
    const int wm = wave & 1, wn = wave >> 1;

    const int row0 = tid >> 2,        kc0 = tid & 3;          // 512 16B-chunks, 2/thread
    const int row1 = (tid+256) >> 2,  kc1 = tid & 3;

    const f32x4 vz = {0.f, 0.f, 0.f, 0.f};
    f32x4 acc[4][4];
    #pragma unroll
    for (int i = 0; i < 4; ++i)
        #pragma unroll
        for (int j = 0; j < 4; ++j) acc[i][j] = vz;

    const int fr = lane & 15, kg = lane >> 4;

    for (int kt = 0; kt < H_/32; ++kt) {
        const int k0 = kt*32;
        __syncthreads();
        *(uint4*)(Al + row0*AST + kc0*8) = *(const uint4*)(Yh + (m0+row0)*H_ + k0 + kc0*8);
        *(uint4*)(Al + row1*AST + kc1*8) = *(const uint4*)(Yh + (m0+row1)*H_ + k0 + kc1*8);
        *(uint4*)(Bl + row0*AST + kc0*8) = *(const uint4*)(WL + (long)(n0+row0)*H_ + k0 + kc0*8);
        *(uint4*)(Bl + row1*AST + kc1*8) = *(const uint4*)(WL + (long)(n0+row1)*H_ + k0 + kc1*8);
        __syncthreads();
        f16x8 af[4], bf[4];
        #pragma unroll
        for (int x = 0; x < 4; ++x) {
            af[x] = *(const f16x8*)(Al + (wm*64 + x*16 + fr)*AST + kg*8);
            bf[x] = *(const f16x8*)(Bl + (wn*64 + x*16 + fr)*AST + kg*8);
        }
        #pragma unroll
        for (int mi = 0; mi < 4; ++mi)
            #pragma unroll
            for (int ni = 0; ni < 4; ++ni)
                acc[mi][ni] = __builtin_amdgcn_mfma_f32_16x16x32_f16(
                                  af[mi], bf[ni], acc[mi][ni], 0, 0, 0);
    }
    // epilogue: C/D layout col=lane&15, row=(lane>>4)*4+reg
    const int col = lane & 15;
    const int rb  = (lane >> 4) * 4;
    #pragma unroll
    for (int mi = 0; mi < 4; ++mi) {
        const long grow = m0 + wm*64 + mi*16 + rb;
        #pragma unroll
        for (int ni = 0; ni < 4; ++ni) {
            const int gcol = n0 + wn*64 + ni*16 + col;
            const float bias = b_lin[gcol];
            #pragma unroll
            for (int q = 0; q < 4; ++q)
                d_out[(grow + q)*V_ + gcol] = acc[mi][ni][q] + bias;
        }
    }
}

extern "C" void kernel_launch(void* const* d_in, const int* in_sizes, int n_in,
                              void* d_out, int out_size, void* d_ws, size_t ws_size,
                              hipStream_t stream)
{
    const int*   tokens = (const int*)  d_in[0];   // (B,S) int32 (jax demotes int64)
    const float* state  = (const float*)d_in[1];   // (1,B,H)
    const float* W_ih   = (const float*)d_in[2];   // (H,V)
    const float* b_ih   = (const float*)d_in[3];
    const float* W_hh   = (const float*)d_in[4];   // (H,H)
    const float* b_hh   = (const float*)d_in[5];
    const float* W_lin  = (const float*)d_in[6];   // (V,H)
    const float* b_lin  = (const float*)d_in[7];
    char*  ws  = (char*)d_ws;
    float* out = (float*)d_out;

    // total prep work items: 2*V*H + S*B + B*H + 256 = 4,260,096 -> 16641 blocks
    prep_kernel<<<16641, 256, 0, stream>>>(tokens, state, W_ih, b_ih, b_hh, W_lin, ws);
    rnn_kernel<<<256, 256, 0, stream>>>(W_hh, ws, out);
    out_gemm<<<4096, 256, 0, stream>>>(ws, b_lin, out);
}

// Round 3
// 3956.358 us; speedup vs baseline: 9.4484x; 1.3050x over previous
//
#include <hip/hip_runtime.h>

// Problem: tanh-RNN. inputs (B,S) int tokens; x_proj = W_ih^T[token] + b_ih + b_hh;
// h_t = tanh(x_t + h_{t-1} @ W_hh^T); out = Y @ W_lin^T + b_lin ; also return h_T.
#define B_ 32
#define S_ 1024
#define V_ 2048
#define H_ 1024
#define OUT_ELEMS (S_*B_*V_)   // 67108864 fp32 outputs, then B_*H_ fp32 h_T tail

typedef _Float16 f16;
typedef __attribute__((ext_vector_type(2))) _Float16 f16x2;
typedef __attribute__((ext_vector_type(8))) _Float16 f16x8;
typedef __attribute__((ext_vector_type(4))) float    f32x4;

// ---- workspace layout (bytes) ----
#define WS_YH    0ul                  // S*B*H f16  = 64 MB   (Y, fp16, row = t*B+b)
#define WS_E     67108864ul           // V*H  f32   = 8 MB    (E[v][i] = W_ih[i][v]+b_ih[i]+b_hh[i])
#define WS_WL16  75497472ul           // V*H  f16   = 4 MB    (W_lin cast)
#define WS_H16   79691776ul           // 2*B*H f16  = 128 KB  (h double buffer)
#define WS_TOK   79822848ul           // S*B  i32   = 128 KB  (tokens transposed [t][b])
#define WS_FLAGS 79953920ul           // 256 u32              (group barrier flags)

#if __has_builtin(__builtin_amdgcn_fdot2)
#define FDOT2(a,b,c) __builtin_amdgcn_fdot2((a),(b),(c),false)
#else
#define FDOT2(a,b,c) ((float)(a)[0]*(float)(b)[0] + (float)(a)[1]*(float)(b)[1] + (c))
#endif
#define PAIR(v,q) (__builtin_shufflevector((v),(v), 2*(q), 2*(q)+1))

// System-scope (MALL-coherent) accesses — proven protocol from the 4.78ms version.
__device__ __forceinline__ void stc(void* p, unsigned v) {
    asm volatile("global_store_dword %0, %1, off sc0 sc1" :: "v"(p), "v"(v) : "memory");
}
__device__ __forceinline__ unsigned ldc(const void* p) {
    unsigned v;
    asm volatile("global_load_dword %0, %1, off sc0 sc1\n\ts_waitcnt vmcnt(0)"
                 : "=v"(v) : "v"(p) : "memory");
    return v;
}

// ---------------- prep: build E, cast W_lin, transpose tokens, init h0, zero flags -----
__global__ void prep_kernel(const int* __restrict__ tok_in,   // (B,S) int32
                            const float* __restrict__ state,  // (1,B,H)
                            const float* __restrict__ W_ih,   // (H,V)
                            const float* __restrict__ b_ih,
                            const float* __restrict__ b_hh,
                            const float* __restrict__ W_lin,  // (V,H)
                            char* __restrict__ ws)
{
    float* E      = (float*)(ws + WS_E);
    f16*   WL     = (f16*)  (ws + WS_WL16);
    f16*   h16    = (f16*)  (ws + WS_H16);
    int*   tok    = (int*)  (ws + WS_TOK);
    unsigned* flg = (unsigned*)(ws + WS_FLAGS);

    long idx = (long)blockIdx.x * blockDim.x + threadIdx.x;
    if (idx < (long)V_*H_) {                 // E build: lanes consecutive in v -> coalesced W_ih reads
        int i = (int)(idx >> 11);            // / V_
        int v = (int)(idx & (V_-1));
        E[(long)v*H_ + i] = W_ih[(long)i*V_ + v] + b_ih[i] + b_hh[i];
        return;
    }
    long o = idx - (long)V_*H_;
    if (o < (long)V_*H_) { WL[o] = (f16)W_lin[o]; return; }
    long o2 = o - (long)V_*H_;
    if (o2 < S_*B_) {                        // tok[t][b] = inputs[b][t]
        int t = (int)(o2 >> 5), b = (int)(o2 & 31);
        tok[o2] = tok_in[b*S_ + t];
        return;
    }
    long o3 = o2 - S_*B_;
    if (o3 < B_*H_) { h16[o3] = (f16)state[o3]; return; }
    long o4 = o3 - B_*H_;
    if (o4 < 256) flg[o4] = 0u;
}

// ---------------- persistent recurrence ----------------
// 256 blocks: bg = blockIdx%8 (batch group of 4), hb = blockIdx/8 (32 hidden rows).
// Proven sc0/sc1 system-scope exchange + 32-flag barrier (4.78ms skeleton). New this
// round (all off the sync protocol): W_hh hoisted into 64 VGPRs with the bank-rotation
// baked into the REGISTER index (static indices, rule #20); h LDS reads rotated
// (8-way -> 2-way bank conflict); token prefetched one step ahead; E-gather issued
// before the dot loop (latency hidden under compute); epilogue parallel across lanes
// (lane jp&3 owns batch jp&3; stores split jp<4 -> h coherent, jp>=4 -> Y plain).
__launch_bounds__(256, 1)
__global__ void rnn_kernel(const float* __restrict__ W_hh,
                           char* __restrict__ ws,
                           float* __restrict__ d_out)
{
    __shared__ f16 Wt[32 * H_];                   // 64 KB (staging for W->regs)
    __shared__ __align__(16) f16 hl[4 * H_];      // 8 KB staged h (4 batches x H)

    const int tid = threadIdx.x;
    const int bg  = blockIdx.x & 7;
    const int hb  = blockIdx.x >> 3;
    const int i0  = hb * 32;

    float* E       = (float*)(ws + WS_E);
    f16*   Yh      = (f16*)  (ws + WS_YH);
    f16*   h16     = (f16*)  (ws + WS_H16);
    const int* tok = (const int*)(ws + WS_TOK);
    unsigned* flg  = (unsigned*)(ws + WS_FLAGS);
    const int myflag = bg*32 + hb;

    // Load W slice into swizzled LDS: j-pair p=(j>>1) at dword p*32 + ((r + 4*(j>>7)) & 31)
    for (int e = tid; e < 32*H_; e += 256) {
        int rr = e >> 10, j = e & (H_-1);
        int slot = (rr + 4*(j >> 7)) & 31;
        Wt[(((j>>1)*32 + slot) << 1) | (j & 1)] = (f16)W_hh[(long)(i0+rr)*H_ + j];
    }
    __syncthreads();

    const int jp = tid & 7;          // 8 j-slices of 128
    const int r  = tid >> 3;         // 32 rows
    const f16x2* Wd = (const f16x2*)Wt;
    const int wbase = jp*2048 + ((r + 4*jp) & 31);

    // Hoist W into registers; rotation (i+2jp)&15 baked into the register index at load
    // time so all inner-loop register indices are compile-time constants.
    f16x2 w[16][4];
    #pragma unroll
    for (int i = 0; i < 16; ++i) {
        const int cc = (i + 2*jp) & 15;
        #pragma unroll
        for (int q = 0; q < 4; ++q) w[i][q] = Wd[wbase + cc*128 + q*32];
    }

    unsigned long long* const l64 = (unsigned long long*)hl;
    const int b  = jp & 3;           // this lane's batch (jp>=4 duplicates for Y stores)
    const int gb = bg*4 + b;

    int tok_cur = tok[gb];           // token for t=0

    for (int t = 0; t < S_; ++t) {
        const int cur = t & 1, nxt = cur ^ 1;

        // ---- stage h[cur] for our 4 batches (8 KB) via system-scope loads ----
        {
            const unsigned long long* s64 =
                (const unsigned long long*)(h16 + (long)cur*(B_*H_) + (long)(bg*4)*H_);
            unsigned long long d0, d1, d2, d3;
            asm volatile("global_load_dwordx2 %0, %1, off sc0 sc1" : "=v"(d0) : "v"(s64 + tid      ) : "memory");
            asm volatile("global_load_dwordx2 %0, %1, off sc0 sc1" : "=v"(d1) : "v"(s64 + tid + 256) : "memory");
            asm volatile("global_load_dwordx2 %0, %1, off sc0 sc1" : "=v"(d2) : "v"(s64 + tid + 512) : "memory");
            asm volatile("global_load_dwordx2 %0, %1, off sc0 sc1" : "=v"(d3) : "v"(s64 + tid + 768) : "memory");
            asm volatile("s_waitcnt vmcnt(0)" ::: "memory");
            l64[tid      ] = d0;
            l64[tid + 256] = d1;
            l64[tid + 512] = d2;
            l64[tid + 768] = d3;
        }
        __syncthreads();

        // ---- issue E gather now (latency hides under the dot loop) ----
        float ef;
        {
            const float* ep = E + (long)tok_cur*H_ + i0 + r;
            asm volatile("global_load_dword %0, %1, off" : "=v"(ef) : "v"(ep) : "memory");
        }
        // prefetch next step's token (plain load; compiler inserts the wait at use)
        const int tn = (t+1 < S_) ? (t+1) : 0;
        const int tok_nxt = tok[tn*B_ + gb];

        float a0=0.f, a1=0.f, a2=0.f, a3=0.f;
        #pragma unroll
        for (int i = 0; i < 16; ++i) {
            const int cc = (i + 2*jp) & 15;     // matches w[i][*]'s load rotation
            const f16* hp = hl + jp*128 + cc*8;
            f16x8 v0 = *(const f16x8*)(hp + 0*H_);
            f16x8 v1 = *(const f16x8*)(hp + 1*H_);
            f16x8 v2 = *(const f16x8*)(hp + 2*H_);
            f16x8 v3 = *(const f16x8*)(hp + 3*H_);
            a0 = FDOT2(w[i][0], PAIR(v0,0), a0); a0 = FDOT2(w[i][1], PAIR(v0,1), a0);
            a0 = FDOT2(w[i][2], PAIR(v0,2), a0); a0 = FDOT2(w[i][3], PAIR(v0,3), a0);
            a1 = FDOT2(w[i][0], PAIR(v1,0), a1); a1 = FDOT2(w[i][1], PAIR(v1,1), a1);
            a1 = FDOT2(w[i][2], PAIR(v1,2), a1); a1 = FDOT2(w[i][3], PAIR(v1,3), a1);
            a2 = FDOT2(w[i][0], PAIR(v2,0), a2); a2 = FDOT2(w[i][1], PAIR(v2,1), a2);
            a2 = FDOT2(w[i][2], PAIR(v2,2), a2); a2 = FDOT2(w[i][3], PAIR(v2,3), a2);
            a3 = FDOT2(w[i][0], PAIR(v3,0), a3); a3 = FDOT2(w[i][1], PAIR(v3,1), a3);
            a3 = FDOT2(w[i][2], PAIR(v3,2), a3); a3 = FDOT2(w[i][3], PAIR(v3,3), a3);
        }
        // butterfly over jp: afterwards EVERY lane holds all four full sums
        a0 += __shfl_xor(a0,1); a0 += __shfl_xor(a0,2); a0 += __shfl_xor(a0,4);
        a1 += __shfl_xor(a1,1); a1 += __shfl_xor(a1,2); a1 += __shfl_xor(a1,4);
        a2 += __shfl_xor(a2,1); a2 += __shfl_xor(a2,2); a2 += __shfl_xor(a2,4);
        a3 += __shfl_xor(a3,1); a3 += __shfl_xor(a3,2); a3 += __shfl_xor(a3,4);

        float hvb = a0;
        if (b == 1) hvb = a1;
        if (b == 2) hvb = a2;
        if (b == 3) hvb = a3;

        asm volatile("s_waitcnt vmcnt(0)" ::: "memory");   // ef (and tok_nxt) ready
        __builtin_amdgcn_sched_barrier(0);                 // rule #18: pin reg-only use
        const float hn = tanhf(ef + hvb);

        // pack rows (r, r+1) into one u32; partner is lane+8 (same jp, r+1; even r only)
        const unsigned hbits = (unsigned)__builtin_bit_cast(unsigned short, (f16)hn);
        const unsigned up    = __shfl_down(hbits, 8);
        const unsigned hpk   = hbits | (up << 16);

        if (!(r & 1)) {
            if (jp < 4) {           // coherent h store (only needed for t < S_-1)
                if (t < S_-1)
                    stc(h16 + (long)nxt*(B_*H_) + (long)gb*H_ + i0 + r, hpk);
            } else {                // Y store handled by the duplicate lanes
                *(unsigned*)(Yh + (long)(t*B_ + gb)*H_ + i0 + r) = hpk;
            }
        }

        if (t < S_-1) {
            // drain all stores to the coherent point, then publish the flag
            asm volatile("s_waitcnt vmcnt(0)" ::: "memory");
            __syncthreads();
            if (tid == 0) stc(flg + myflag, (unsigned)(t+1));
            if (tid < 32) {
                const unsigned tgt = (unsigned)(t+1);
                while (ldc(flg + bg*32 + tid) < tgt)
                    __builtin_amdgcn_s_sleep(1);
            }
            __syncthreads();
        } else {
            if (jp < 4)
                d_out[OUT_ELEMS + gb*H_ + i0 + r] = hn;    // h_T tail (fp32)
        }
        tok_cur = tok_nxt;
    }
}

// ---------------- output GEMM: C = Yh @ WL^T + b_lin (fp16 MFMA, fp32 acc) ------------
#define AST 40   // LDS row stride in f16: 32 + 8 pad -> 16B aligned, frag reads 2-way (free)
__launch_bounds__(256, 2)
__global__ void out_gemm(const char* __restrict__ ws,
                         const float* __restrict__ b_lin,
                         float* __restrict__ d_out)
{
    __shared__ f16 Al[128*AST];
    __shared__ f16 Bl[128*AST];
    const f16* Yh = (const f16*)(ws + WS_YH);
    const f16* WL = (const f16*)(ws + WS_WL16);

    const int tid = threadIdx.x;
    const int nt = blockIdx.x & 15;
    const int mt = blockIdx.x >> 4;
    const long m0 = (long)mt * 128;
    const int  n0 = nt * 128;

    const int lane = tid & 63;
    const int wave = tid >> 6;
    const int wm = wave & 1, wn = wave >> 1;

    const int row0 = tid >> 2,        kc0 = tid & 3;          // 512 16B-chunks, 2/thread
    const int row1 = (tid+256) >> 2,  kc1 = tid & 3;

    const f32x4 vz = {0.f, 0.f, 0.f, 0.f};
    f32x4 acc[4][4];
    #pragma unroll
    for (int i = 0; i < 4; ++i)
        #pragma unroll
        for (int j = 0; j < 4; ++j) acc[i][j] = vz;

    const int fr = lane & 15, kg = lane >> 4;

    for (int kt = 0; kt < H_/32; ++kt) {
        const int k0 = kt*32;
        __syncthreads();
        *(uint4*)(Al + row0*AST + kc0*8) = *(const uint4*)(Yh + (m0+row0)*H_ + k0 + kc0*8);
        *(uint4*)(Al + row1*AST + kc1*8) = *(const uint4*)(Yh + (m0+row1)*H_ + k0 + kc1*8);
        *(uint4*)(Bl + row0*AST + kc0*8) = *(const uint4*)(WL + (long)(n0+row0)*H_ + k0 + kc0*8);
        *(uint4*)(Bl + row1*AST + kc1*8) = *(const uint4*)(WL + (long)(n0+row1)*H_ + k0 + kc1*8);
        __syncthreads();
        f16x8 af[4], bf[4];
        #pragma unroll
        for (int x = 0; x < 4; ++x) {
            af[x] = *(const f16x8*)(Al + (wm*64 + x*16 + fr)*AST + kg*8);
            bf[x] = *(const f16x8*)(Bl + (wn*64 + x*16 + fr)*AST + kg*8);
        }
        #pragma unroll
        for (int mi = 0; mi < 4; ++mi)
            #pragma unroll
            for (int ni = 0; ni < 4; ++ni)
                acc[mi][ni] = __builtin_amdgcn_mfma_f32_16x16x32_f16(
                                  af[mi], bf[ni], acc[mi][ni], 0, 0, 0);
    }
    // epilogue: C/D layout col=lane&15, row=(lane>>4)*4+reg
    const int col = lane & 15;
    const int rb  = (lane >> 4) * 4;
    #pragma unroll
    for (int mi = 0; mi < 4; ++mi) {
        const long grow = m0 + wm*64 + mi*16 + rb;
        #pragma unroll
        for (int ni = 0; ni < 4; ++ni) {
            const int gcol = n0 + wn*64 + ni*16 + col;
            const float bias = b_lin[gcol];
            #pragma unroll
            for (int q = 0; q < 4; ++q)
                d_out[(grow + q)*V_ + gcol] = acc[mi][ni][q] + bias;
        }
    }
}

extern "C" void kernel_launch(void* const* d_in, const int* in_sizes, int n_in,
                              void* d_out, int out_size, void* d_ws, size_t ws_size,
                              hipStream_t stream)
{
    const int*   tokens = (const int*)  d_in[0];   // (B,S) int32 (jax demotes int64)
    const float* state  = (const float*)d_in[1];   // (1,B,H)
    const float* W_ih   = (const float*)d_in[2];   // (H,V)
    const float* b_ih   = (const float*)d_in[3];
    const float* W_hh   = (const float*)d_in[4];   // (H,H)
    const float* b_hh   = (const float*)d_in[5];
    const float* W_lin  = (const float*)d_in[6];   // (V,H)
    const float* b_lin  = (const float*)d_in[7];
    char*  ws  = (char*)d_ws;
    float* out = (float*)d_out;

    // total prep work items: 2*V*H + S*B + B*H + 256 = 4,260,096 -> 16641 blocks
    prep_kernel<<<16641, 256, 0, stream>>>(tokens, state, W_ih, b_ih, b_hh, W_lin, ws);
    rnn_kernel<<<256, 256, 0, stream>>>(W_hh, ws, out);
    out_gemm<<<4096, 256, 0, stream>>>(ws, b_lin, out);
}